// Round 6
// baseline (283.680 us; speedup 1.0000x reference)
//
#include <hip/hip_runtime.h>
#include <hip/hip_bf16.h>
#include <math.h>

#define IN_DIM 256
#define OUT_DIM 64
#define NEG_SLOPE 0.2f
#define LCOLS 80        // 64 h-cols + 16-col score tile (col64=Wa_s, col65=Wa_d)
#define NCH 8           // dst chunks (== XCD count)
#define EBUF_CAP 202752 // per-bucket capacity: E/8 = 200000 + 6.6 sigma margin

typedef __attribute__((ext_vector_type(8))) short bf16x8;
typedef __attribute__((ext_vector_type(4))) float f32x4;

static __device__ __forceinline__ ushort f2bf(float f) {
    union { __hip_bfloat16 b; ushort u; } cv;
    cv.b = __float2bfloat16(f);
    return cv.u;
}
static __device__ __forceinline__ float bf2f(ushort u) {
    union { ushort u2[2]; float f; } cv;
    cv.u2[0] = 0; cv.u2[1] = u;
    return cv.f;
}

// ---------------------------------------------------------------------------
// k0_wa: Wa_s[k] = W[k,:]·a[:64], Wa_d[k] = W[k,:]·a[64:]. One block.
// ---------------------------------------------------------------------------
__global__ __launch_bounds__(256) void k0_wa(
        const float* __restrict__ W, const float* __restrict__ a,
        float* __restrict__ wa)
{
    const int k = threadIdx.x;
    const float* wr = W + (size_t)k * OUT_DIM;
    float ss = 0.f, sd = 0.f;
    #pragma unroll
    for (int j = 0; j < OUT_DIM; ++j) {
        const float w = wr[j];
        ss = fmaf(w, a[j], ss);
        sd = fmaf(w, a[OUT_DIM + j], sd);
    }
    wa[k] = ss;
    wa[IN_DIM + k] = sd;
}

// ---------------------------------------------------------------------------
// k0_swz: pre-swizzled bf16 B-tile (8t x 4khi x 80col x 8j); cols 64/65 = Wa.
// ---------------------------------------------------------------------------
__global__ __launch_bounds__(256) void k0_swz(
        const float* __restrict__ W, const float* __restrict__ wa,
        ushort* __restrict__ wb)
{
    const int idx = blockIdx.x * 256 + threadIdx.x;
    const int j   = idx & 7;
    const int col = (idx >> 3) % LCOLS;
    const int tk  = (idx >> 3) / LCOLS;
    const int k   = (tk >> 2) * 32 + (tk & 3) * 8 + j;
    float v = 0.f;
    if (col < OUT_DIM)           v = W[(size_t)k * OUT_DIM + col];
    else if (col == OUT_DIM)     v = wa[k];
    else if (col == OUT_DIM + 1) v = wa[IN_DIM + k];
    wb[idx] = f2bf(v);
}

// ---------------------------------------------------------------------------
// K1: h = x @ W via bf16 MFMA 16x16x32, scores fused as B-cols 64/65.
// 512 blocks, register-double-buffered x prefetch. (unchanged from R5)
// ---------------------------------------------------------------------------
__global__ __launch_bounds__(256) void k1_mfma(
        const float* __restrict__ x, const ushort* __restrict__ wb,
        ushort* __restrict__ hb, float* __restrict__ s_src,
        float* __restrict__ s_dst, int N, int ngroups)
{
    __shared__ ushort w_lds[8 * 4 * LCOLS * 8];          // 40960 B

    const int tid = threadIdx.x;
    for (int i = tid; i < (8 * 4 * LCOLS * 8) / 8; i += 256)
        ((float4*)w_lds)[i] = ((const float4*)wb)[i];
    __syncthreads();

    const int lane = tid & 63;
    const int l15  = lane & 15;
    const int khi  = lane >> 4;

    const int gw = blockIdx.x * 4 + (tid >> 6);
    const int nw = gridDim.x * 4;

    float4 raw[16];
    int g = gw;
    if (g < ngroups) {
        const int node = min(g * 16 + l15, N - 1);
        const float* xp = x + (size_t)node * IN_DIM + khi * 8;
        #pragma unroll
        for (int t = 0; t < 8; ++t) {
            raw[2 * t]     = *(const float4*)(xp + t * 32);
            raw[2 * t + 1] = *(const float4*)(xp + t * 32 + 4);
        }
    }

    for (; g < ngroups; g += nw) {
        bf16x8 af[8];
        #pragma unroll
        for (int t = 0; t < 8; ++t) {
            union { bf16x8 v; ushort u[8]; } pk;
            pk.u[0] = f2bf(raw[2*t].x);   pk.u[1] = f2bf(raw[2*t].y);
            pk.u[2] = f2bf(raw[2*t].z);   pk.u[3] = f2bf(raw[2*t].w);
            pk.u[4] = f2bf(raw[2*t+1].x); pk.u[5] = f2bf(raw[2*t+1].y);
            pk.u[6] = f2bf(raw[2*t+1].z); pk.u[7] = f2bf(raw[2*t+1].w);
            af[t] = pk.v;
        }

        const int gn = g + nw;
        if (gn < ngroups) {
            const int node = min(gn * 16 + l15, N - 1);
            const float* xp = x + (size_t)node * IN_DIM + khi * 8;
            #pragma unroll
            for (int t = 0; t < 8; ++t) {
                raw[2 * t]     = *(const float4*)(xp + t * 32);
                raw[2 * t + 1] = *(const float4*)(xp + t * 32 + 4);
            }
        }

        f32x4 acc[5] = {{0,0,0,0},{0,0,0,0},{0,0,0,0},{0,0,0,0},{0,0,0,0}};
        #pragma unroll
        for (int t = 0; t < 8; ++t) {
            const bf16x8* wp = (const bf16x8*)w_lds + (t * 4 + khi) * LCOLS + l15;
            #pragma unroll
            for (int c = 0; c < 5; ++c)
                acc[c] = __builtin_amdgcn_mfma_f32_16x16x32_bf16(
                             af[t], wp[c * 16], acc[c], 0, 0, 0);
        }

        const int row0 = g * 16 + khi * 4;
        #pragma unroll
        for (int r = 0; r < 4; ++r) {
            const int nrow = row0 + r;
            if (nrow < N) {
                #pragma unroll
                for (int c = 0; c < 4; ++c)
                    hb[(size_t)nrow * OUT_DIM + c * 16 + l15] = f2bf(acc[c][r]);
                if (l15 == 0) s_src[nrow] = acc[4][r];
                if (l15 == 1) s_dst[nrow] = acc[4][r];
            }
        }
    }
}

// ---------------------------------------------------------------------------
// kA_bin: single pass over edges. Per-dst histogram (fused) + LDS-staged
// radix partition into 8 dst-buckets with append-only sequential writes.
// Entry = src | (local_dst << 17)  (src < 2^17, local_dst < 2^14).
// ---------------------------------------------------------------------------
__global__ __launch_bounds__(256) void kA_bin(
        const int* __restrict__ ei, int* __restrict__ cursor,
        int* __restrict__ gtail, int* __restrict__ ebuf,
        int E, int chunk_n)
{
    __shared__ int lbuf[NCH][256];
    __shared__ int lcnt[NCH];
    __shared__ int lbase[NCH];

    const int tid = threadIdx.x;
    const int e0 = (int)(((long long)blockIdx.x * E) / gridDim.x);
    const int e1 = (int)(((long long)(blockIdx.x + 1) * E) / gridDim.x);

    for (int b = e0; b < e1; b += 256) {
        if (tid < NCH) lcnt[tid] = 0;
        __syncthreads();
        const int i = b + tid;
        if (i < e1) {
            const int src = ei[i];
            const int dst = ei[E + i];
            atomicAdd(&cursor[dst], 1);                   // fused histogram
            const int c = dst / chunk_n;
            const int pos = atomicAdd(&lcnt[c], 1);
            lbuf[c][pos] = src | ((dst - c * chunk_n) << 17);
        }
        __syncthreads();
        if (tid < NCH) lbase[tid] = atomicAdd(&gtail[tid], lcnt[tid]);
        __syncthreads();
        const int c = tid >> 5;                           // 32 threads/bucket
        const int n = lcnt[c];
        for (int idx = (tid & 31); idx < n; idx += 32)
            ebuf[c * EBUF_CAP + lbase[c] + idx] = lbuf[c][idx];
        __syncthreads();
    }
}

// ---------------------------------------------------------------------------
// Exclusive scan of per-dst counts (3 tiny kernels, unchanged).
// ---------------------------------------------------------------------------
__global__ __launch_bounds__(256) void k_scan_block(
        const int* __restrict__ counts, int* __restrict__ base,
        int* __restrict__ partials, int N)
{
    const int t = threadIdx.x;
    const int i = blockIdx.x * 256 + t;
    const int lane = t & 63, wv = t >> 6;
    int v = (i < N) ? counts[i] : 0;
    int s = v;
    #pragma unroll
    for (int off = 1; off < 64; off <<= 1) {
        int u = __shfl_up(s, off, 64);
        if (lane >= off) s += u;
    }
    __shared__ int wsum[4];
    if (lane == 63) wsum[wv] = s;
    __syncthreads();
    if (t == 0) {
        int acc = 0;
        #pragma unroll
        for (int j = 0; j < 4; ++j) { int tmp = wsum[j]; wsum[j] = acc; acc += tmp; }
        partials[blockIdx.x] = acc;
    }
    __syncthreads();
    const int excl = s - v + wsum[wv];
    if (i < N) base[i] = excl;
}

__global__ __launch_bounds__(512) void k_scan_part(int* __restrict__ partials, int NB)
{
    const int t = threadIdx.x;
    const int lane = t & 63, wv = t >> 6;
    int v = (t < NB) ? partials[t] : 0;
    int s = v;
    #pragma unroll
    for (int off = 1; off < 64; off <<= 1) {
        int u = __shfl_up(s, off, 64);
        if (lane >= off) s += u;
    }
    __shared__ int wsum[8];
    if (lane == 63) wsum[wv] = s;
    __syncthreads();
    if (t == 0) {
        int acc = 0;
        #pragma unroll
        for (int j = 0; j < 8; ++j) { int tmp = wsum[j]; wsum[j] = acc; acc += tmp; }
    }
    __syncthreads();
    const int excl = s - v + wsum[wv];
    if (t < NB) partials[t] = excl;
}

__global__ __launch_bounds__(256) void k_scan_add(
        int* __restrict__ base, const int* __restrict__ partials,
        int* __restrict__ cursor, int N, int E)
{
    const int i = blockIdx.x * 256 + threadIdx.x;
    if (i < N) {
        const int b = base[i] + partials[blockIdx.x];
        base[i] = b;
        cursor[i] = b;
    }
    if (i == 0) base[N] = E;
}

// ---------------------------------------------------------------------------
// kB_scatter: bucket c read SEQUENTIALLY; scatter src into exact-CSR chunk
// region (~0.8 MB, co-XCD writers via blockIdx&7). No edge re-reads.
// ---------------------------------------------------------------------------
__global__ __launch_bounds__(256) void kB_scatter(
        const int* __restrict__ ebuf, const int* __restrict__ gtail,
        int* __restrict__ cursor, int* __restrict__ csr, int chunk_n)
{
    const int c  = blockIdx.x & 7;
    const int g  = blockIdx.x >> 3;
    const int ng = gridDim.x >> 3;
    const int n  = gtail[c];
    const int e0 = (int)(((long long)g * n) / ng);
    const int e1 = (int)(((long long)(g + 1) * n) / ng);
    const int dbase = c * chunk_n;
    const int* eb = ebuf + c * EBUF_CAP;
    for (int i = e0 + threadIdx.x; i < e1; i += 256) {
        const int p = eb[i];
        const int src = p & 0x1FFFF;
        const int dst = dbase + (p >> 17);
        const int pos = atomicAdd(&cursor[dst], 1);
        csr[pos] = src;
    }
}

// ---------------------------------------------------------------------------
// K2: quarter-wave (16 lanes) per dst node. Scoring: coalesced 4B csr load +
// L2-resident s_src gather + exp; 4-step den reduce; shfl-broadcast FMA loop.
// ---------------------------------------------------------------------------
__global__ __launch_bounds__(256) void k2_gather(
        const int* __restrict__ csr, const int* __restrict__ base,
        const ushort* __restrict__ hb, const float* __restrict__ s_src,
        const float* __restrict__ s_dst, float* __restrict__ out, int N)
{
    const int w = blockIdx.x * 16 + (threadIdx.x >> 4);
    if (w >= N) return;
    const int l15   = threadIdx.x & 15;
    const int qbase = threadIdx.x & 48;

    const int beg = base[w];
    const int end = base[w + 1];
    const float sd = s_dst[w];

    float a0 = 0.f, a1 = 0.f, a2 = 0.f, a3 = 0.f, den = 0.f;

    for (int b = beg; b < end; b += 16) {
        const int cnt = min(16, end - b);
        int   srcj = 0;
        float exj  = 0.f;
        if (l15 < cnt) {
            srcj = csr[b + l15];
            float sc = s_src[srcj] + sd;
            sc = (sc > 0.f) ? sc : NEG_SLOPE * sc;
            exj = __expf(sc);
        }
        float t = exj;
        t += __shfl_xor(t, 1, 64);
        t += __shfl_xor(t, 2, 64);
        t += __shfl_xor(t, 4, 64);
        t += __shfl_xor(t, 8, 64);
        den += t;

        #pragma unroll 4
        for (int j = 0; j < cnt; ++j) {
            const int   s  = __shfl(srcj, qbase + j, 64);
            const float ex = __shfl(exj,  qbase + j, 64);
            const ushort4 hv = *(const ushort4*)(hb + ((size_t)s << 6) + (l15 << 2));
            a0 = fmaf(ex, bf2f(hv.x), a0);
            a1 = fmaf(ex, bf2f(hv.y), a1);
            a2 = fmaf(ex, bf2f(hv.z), a2);
            a3 = fmaf(ex, bf2f(hv.w), a3);
        }
    }

    const float r = (end > beg) ? 1.f / den : 0.f;
    float4 v;
    v.x = a0 * r; v.y = a1 * r; v.z = a2 * r; v.w = a3 * r;
    *(float4*)(out + ((size_t)w << 6) + (l15 << 2)) = v;
}

extern "C" void kernel_launch(void* const* d_in, const int* in_sizes, int n_in,
                              void* d_out, int out_size, void* d_ws, size_t ws_size,
                              hipStream_t stream)
{
    const float* x  = (const float*)d_in[0];
    const float* W  = (const float*)d_in[1];
    const float* a  = (const float*)d_in[2];
    const int*   ei = (const int*)d_in[3];

    const int N = in_sizes[0] / IN_DIM;     // 100000
    const int E = in_sizes[3] / 2;          // 1600000

    float* out = (float*)d_out;

    char* ws = (char*)d_ws;
    ushort* hb     = (ushort*)ws;                  ws += (size_t)N * OUT_DIM * 2; // 12.8 MB
    float*  s_src  = (float*)ws;                   ws += (size_t)N * 4;
    float*  s_dst  = (float*)ws;                   ws += (size_t)N * 4;
    int*    base   = (int*)ws;                     ws += (size_t)(N + 1) * 4;
    int*    cursor = (int*)ws;                     ws += (size_t)N * 4;
    int*    gtail  = (int*)ws;                     ws += NCH * 4;     // adjacent to cursor
    int*    parts  = (int*)ws;                     ws += 512 * 4;
    float*  wa     = (float*)ws;                   ws += 2 * IN_DIM * 4;
    ushort* wb     = (ushort*)ws;                  ws += 8 * 4 * LCOLS * 8 * 2;   // 40 KB
    int*    ebuf   = (int*)ws;                     ws += (size_t)NCH * EBUF_CAP * 4; // 6.5 MB
    int*    csr    = (int*)ws;                     ws += (size_t)E * 4;           // 6.4 MB

    const int NB = (N + 255) / 256;
    const int chunk_n = (N + 7) / 8;               // 12500

    // zero cursor + gtail in one shot (adjacent)
    hipMemsetAsync(cursor, 0, (size_t)(N + NCH) * 4, stream);

    // radix partition + fused histogram
    kA_bin<<<2048, 256, 0, stream>>>(ei, cursor, gtail, ebuf, E, chunk_n);

    // exact CSR offsets
    k_scan_block<<<NB, 256, 0, stream>>>(cursor, base, parts, N);
    k_scan_part<<<1, 512, 0, stream>>>(parts, NB);
    k_scan_add<<<NB, 256, 0, stream>>>(base, parts, cursor, N, E);

    // node GEMM with fused score columns
    k0_wa<<<1, 256, 0, stream>>>(W, a, wa);
    k0_swz<<<(8 * 4 * LCOLS * 8) / 256, 256, 0, stream>>>(W, wa, wb);
    const int ngroups = (N + 15) / 16;
    k1_mfma<<<512, 256, 0, stream>>>(x, wb, hb, s_src, s_dst, N, ngroups);

    // bucket-local scatter, then fused gather + normalize
    kB_scatter<<<2048, 256, 0, stream>>>(ebuf, gtail, cursor, csr, chunk_n);
    k2_gather<<<(N + 15) / 16, 256, 0, stream>>>(csr, base, hb, s_src, s_dst, out, N);
}

// Round 7
// 242.566 us; speedup vs baseline: 1.1695x; 1.1695x over previous
//
#include <hip/hip_runtime.h>
#include <hip/hip_bf16.h>
#include <math.h>

#define IN_DIM 256
#define OUT_DIM 64
#define NEG_SLOPE 0.2f
#define LCOLS 80   // 64 h-cols + 16-col score tile (col64=Wa_s, col65=Wa_d)

typedef __attribute__((ext_vector_type(8))) short bf16x8;
typedef __attribute__((ext_vector_type(4))) float f32x4;

static __device__ __forceinline__ ushort f2bf(float f) {
    union { __hip_bfloat16 b; ushort u; } cv;
    cv.b = __float2bfloat16(f);
    return cv.u;
}
static __device__ __forceinline__ float bf2f(ushort u) {
    union { ushort u2[2]; float f; } cv;
    cv.u2[0] = 0; cv.u2[1] = u;
    return cv.f;
}

// ---------------------------------------------------------------------------
// k0_wa: Wa_s[k] = W[k,:]·a[:64], Wa_d[k] = W[k,:]·a[64:]. One block.
// ---------------------------------------------------------------------------
__global__ __launch_bounds__(256) void k0_wa(
        const float* __restrict__ W, const float* __restrict__ a,
        float* __restrict__ wa)
{
    const int k = threadIdx.x;
    const float* wr = W + (size_t)k * OUT_DIM;
    float ss = 0.f, sd = 0.f;
    #pragma unroll
    for (int j = 0; j < OUT_DIM; ++j) {
        const float w = wr[j];
        ss = fmaf(w, a[j], ss);
        sd = fmaf(w, a[OUT_DIM + j], sd);
    }
    wa[k] = ss;
    wa[IN_DIM + k] = sd;
}

// ---------------------------------------------------------------------------
// k0_swz: pre-swizzled bf16 B-tile (8t x 4khi x 80col x 8j); cols 64/65 = Wa.
// ---------------------------------------------------------------------------
__global__ __launch_bounds__(256) void k0_swz(
        const float* __restrict__ W, const float* __restrict__ wa,
        ushort* __restrict__ wb)
{
    const int idx = blockIdx.x * 256 + threadIdx.x;
    const int j   = idx & 7;
    const int col = (idx >> 3) % LCOLS;
    const int tk  = (idx >> 3) / LCOLS;
    const int k   = (tk >> 2) * 32 + (tk & 3) * 8 + j;
    float v = 0.f;
    if (col < OUT_DIM)           v = W[(size_t)k * OUT_DIM + col];
    else if (col == OUT_DIM)     v = wa[k];
    else if (col == OUT_DIM + 1) v = wa[IN_DIM + k];
    wb[idx] = f2bf(v);
}

// ---------------------------------------------------------------------------
// K1: h = x @ W via bf16 MFMA 16x16x32, scores fused as B-cols 64/65.
// grid 1024 (4 blocks/CU with 40KB LDS -> 16 waves/CU), register-double-
// buffered x prefetch, grid-stride over 16-node groups.
// ---------------------------------------------------------------------------
__global__ __launch_bounds__(256) void k1_mfma(
        const float* __restrict__ x, const ushort* __restrict__ wb,
        ushort* __restrict__ hb, float* __restrict__ s_src,
        float* __restrict__ s_dst, int N, int ngroups)
{
    __shared__ ushort w_lds[8 * 4 * LCOLS * 8];          // 40960 B

    const int tid = threadIdx.x;
    for (int i = tid; i < (8 * 4 * LCOLS * 8) / 8; i += 256)
        ((float4*)w_lds)[i] = ((const float4*)wb)[i];
    __syncthreads();

    const int lane = tid & 63;
    const int l15  = lane & 15;
    const int khi  = lane >> 4;

    const int gw = blockIdx.x * 4 + (tid >> 6);
    const int nw = gridDim.x * 4;

    float4 raw[16];
    int g = gw;
    if (g < ngroups) {
        const int node = min(g * 16 + l15, N - 1);
        const float* xp = x + (size_t)node * IN_DIM + khi * 8;
        #pragma unroll
        for (int t = 0; t < 8; ++t) {
            raw[2 * t]     = *(const float4*)(xp + t * 32);
            raw[2 * t + 1] = *(const float4*)(xp + t * 32 + 4);
        }
    }

    for (; g < ngroups; g += nw) {
        bf16x8 af[8];
        #pragma unroll
        for (int t = 0; t < 8; ++t) {
            union { bf16x8 v; ushort u[8]; } pk;
            pk.u[0] = f2bf(raw[2*t].x);   pk.u[1] = f2bf(raw[2*t].y);
            pk.u[2] = f2bf(raw[2*t].z);   pk.u[3] = f2bf(raw[2*t].w);
            pk.u[4] = f2bf(raw[2*t+1].x); pk.u[5] = f2bf(raw[2*t+1].y);
            pk.u[6] = f2bf(raw[2*t+1].z); pk.u[7] = f2bf(raw[2*t+1].w);
            af[t] = pk.v;
        }

        const int gn = g + nw;
        if (gn < ngroups) {
            const int node = min(gn * 16 + l15, N - 1);
            const float* xp = x + (size_t)node * IN_DIM + khi * 8;
            #pragma unroll
            for (int t = 0; t < 8; ++t) {
                raw[2 * t]     = *(const float4*)(xp + t * 32);
                raw[2 * t + 1] = *(const float4*)(xp + t * 32 + 4);
            }
        }

        f32x4 acc[5] = {{0,0,0,0},{0,0,0,0},{0,0,0,0},{0,0,0,0},{0,0,0,0}};
        #pragma unroll
        for (int t = 0; t < 8; ++t) {
            const bf16x8* wp = (const bf16x8*)w_lds + (t * 4 + khi) * LCOLS + l15;
            #pragma unroll
            for (int c = 0; c < 5; ++c)
                acc[c] = __builtin_amdgcn_mfma_f32_16x16x32_bf16(
                             af[t], wp[c * 16], acc[c], 0, 0, 0);
        }

        const int row0 = g * 16 + khi * 4;
        #pragma unroll
        for (int r = 0; r < 4; ++r) {
            const int nrow = row0 + r;
            if (nrow < N) {
                #pragma unroll
                for (int c = 0; c < 4; ++c)
                    hb[(size_t)nrow * OUT_DIM + c * 16 + l15] = f2bf(acc[c][r]);
                if (l15 == 0) s_src[nrow] = acc[4][r];
                if (l15 == 1) s_dst[nrow] = acc[4][r];
            }
        }
    }
}

// ---------------------------------------------------------------------------
// CSR build: hist -> 3-kernel exclusive scan -> chunked scatter.
// ---------------------------------------------------------------------------
__global__ __launch_bounds__(256) void k_hist(
        const int* __restrict__ dst, int* __restrict__ cursor, int E4)
{
    int i = blockIdx.x * blockDim.x + threadIdx.x;
    const int strd = gridDim.x * blockDim.x;
    for (; i < E4; i += strd) {
        const int4 d = ((const int4*)dst)[i];
        atomicAdd(&cursor[d.x], 1);
        atomicAdd(&cursor[d.y], 1);
        atomicAdd(&cursor[d.z], 1);
        atomicAdd(&cursor[d.w], 1);
    }
}

__global__ __launch_bounds__(256) void k_scan_block(
        const int* __restrict__ counts, int* __restrict__ base,
        int* __restrict__ partials, int N)
{
    const int t = threadIdx.x;
    const int i = blockIdx.x * 256 + t;
    const int lane = t & 63, wv = t >> 6;
    int v = (i < N) ? counts[i] : 0;
    int s = v;
    #pragma unroll
    for (int off = 1; off < 64; off <<= 1) {
        int u = __shfl_up(s, off, 64);
        if (lane >= off) s += u;
    }
    __shared__ int wsum[4];
    if (lane == 63) wsum[wv] = s;
    __syncthreads();
    if (t == 0) {
        int acc = 0;
        #pragma unroll
        for (int j = 0; j < 4; ++j) { int tmp = wsum[j]; wsum[j] = acc; acc += tmp; }
        partials[blockIdx.x] = acc;
    }
    __syncthreads();
    const int excl = s - v + wsum[wv];
    if (i < N) base[i] = excl;
}

__global__ __launch_bounds__(512) void k_scan_part(int* __restrict__ partials, int NB)
{
    const int t = threadIdx.x;
    const int lane = t & 63, wv = t >> 6;
    int v = (t < NB) ? partials[t] : 0;
    int s = v;
    #pragma unroll
    for (int off = 1; off < 64; off <<= 1) {
        int u = __shfl_up(s, off, 64);
        if (lane >= off) s += u;
    }
    __shared__ int wsum[8];
    if (lane == 63) wsum[wv] = s;
    __syncthreads();
    if (t == 0) {
        int acc = 0;
        #pragma unroll
        for (int j = 0; j < 8; ++j) { int tmp = wsum[j]; wsum[j] = acc; acc += tmp; }
    }
    __syncthreads();
    const int excl = s - v + wsum[wv];
    if (t < NB) partials[t] = excl;
}

__global__ __launch_bounds__(256) void k_scan_add(
        int* __restrict__ base, const int* __restrict__ partials,
        int* __restrict__ cursor, int N, int E)
{
    const int i = blockIdx.x * 256 + threadIdx.x;
    if (i < N) {
        const int b = base[i] + partials[blockIdx.x];
        base[i] = b;
        cursor[i] = b;
    }
    if (i == 0) base[N] = E;
}

// Chunked scatter (R4-proven): block b owns dst-chunk (b&7) [~0.8 MB csr
// region, one XCD's L2 via round-robin block->XCD] and edge-slice (b>>3).
// 4B entries (src only) — score recomputed in k2 from L2-resident s_src.
__global__ __launch_bounds__(256) void k_scatter8(
        const int* __restrict__ ei, int* __restrict__ cursor,
        int* __restrict__ csr, int E, int chunk_n)
{
    const int c  = blockIdx.x & 7;
    const int g  = blockIdx.x >> 3;
    const int ng = gridDim.x >> 3;
    const int lo = c * chunk_n, hi = lo + chunk_n;
    const int e0 = (int)(((long long)g * E) / ng);
    const int e1 = (int)(((long long)(g + 1) * E) / ng);
    for (int i = e0 + threadIdx.x; i < e1; i += 256) {
        const int dst = ei[E + i];
        if (dst >= lo && dst < hi) {
            const int pos = atomicAdd(&cursor[dst], 1);
            csr[pos] = ei[i];
        }
    }
}

// ---------------------------------------------------------------------------
// K2: quarter-wave (16 lanes) per dst node. Coalesced 4B csr load +
// L2-resident s_src gather + exp; 4-step den reduce; shfl-broadcast FMA loop.
// ---------------------------------------------------------------------------
__global__ __launch_bounds__(256) void k2_gather(
        const int* __restrict__ csr, const int* __restrict__ base,
        const ushort* __restrict__ hb, const float* __restrict__ s_src,
        const float* __restrict__ s_dst, float* __restrict__ out, int N)
{
    const int w = blockIdx.x * 16 + (threadIdx.x >> 4);
    if (w >= N) return;
    const int l15   = threadIdx.x & 15;
    const int qbase = threadIdx.x & 48;

    const int beg = base[w];
    const int end = base[w + 1];
    const float sd = s_dst[w];

    float a0 = 0.f, a1 = 0.f, a2 = 0.f, a3 = 0.f, den = 0.f;

    for (int b = beg; b < end; b += 16) {
        const int cnt = min(16, end - b);
        int   srcj = 0;
        float exj  = 0.f;
        if (l15 < cnt) {
            srcj = csr[b + l15];
            float sc = s_src[srcj] + sd;
            sc = (sc > 0.f) ? sc : NEG_SLOPE * sc;
            exj = __expf(sc);
        }
        float t = exj;
        t += __shfl_xor(t, 1, 64);
        t += __shfl_xor(t, 2, 64);
        t += __shfl_xor(t, 4, 64);
        t += __shfl_xor(t, 8, 64);
        den += t;

        #pragma unroll 4
        for (int j = 0; j < cnt; ++j) {
            const int   s  = __shfl(srcj, qbase + j, 64);
            const float ex = __shfl(exj,  qbase + j, 64);
            const ushort4 hv = *(const ushort4*)(hb + ((size_t)s << 6) + (l15 << 2));
            a0 = fmaf(ex, bf2f(hv.x), a0);
            a1 = fmaf(ex, bf2f(hv.y), a1);
            a2 = fmaf(ex, bf2f(hv.z), a2);
            a3 = fmaf(ex, bf2f(hv.w), a3);
        }
    }

    const float r = (end > beg) ? 1.f / den : 0.f;
    float4 v;
    v.x = a0 * r; v.y = a1 * r; v.z = a2 * r; v.w = a3 * r;
    *(float4*)(out + ((size_t)w << 6) + (l15 << 2)) = v;
}

extern "C" void kernel_launch(void* const* d_in, const int* in_sizes, int n_in,
                              void* d_out, int out_size, void* d_ws, size_t ws_size,
                              hipStream_t stream)
{
    const float* x  = (const float*)d_in[0];
    const float* W  = (const float*)d_in[1];
    const float* a  = (const float*)d_in[2];
    const int*   ei = (const int*)d_in[3];

    const int N = in_sizes[0] / IN_DIM;     // 100000
    const int E = in_sizes[3] / 2;          // 1600000

    float* out = (float*)d_out;

    char* ws = (char*)d_ws;
    ushort* hb     = (ushort*)ws;                  ws += (size_t)N * OUT_DIM * 2; // 12.8 MB
    float*  s_src  = (float*)ws;                   ws += (size_t)N * 4;
    float*  s_dst  = (float*)ws;                   ws += (size_t)N * 4;
    int*    base   = (int*)ws;                     ws += (size_t)(N + 1) * 4;
    int*    cursor = (int*)ws;                     ws += (size_t)N * 4;
    int*    parts  = (int*)ws;                     ws += 512 * 4;
    float*  wa     = (float*)ws;                   ws += 2 * IN_DIM * 4;
    ushort* wb     = (ushort*)ws;                  ws += 8 * 4 * LCOLS * 8 * 2;   // 40 KB
    int*    csr    = (int*)ws;                     ws += (size_t)E * 4;           // 6.4 MB

    const int NB = (N + 255) / 256;
    const int chunk_n = (N + 7) / 8;               // 12500

    hipMemsetAsync(cursor, 0, (size_t)N * 4, stream);

    // CSR counts + offsets
    k_hist<<<2048, 256, 0, stream>>>(ei + E, cursor, E / 4);
    k_scan_block<<<NB, 256, 0, stream>>>(cursor, base, parts, N);
    k_scan_part<<<1, 512, 0, stream>>>(parts, NB);
    k_scan_add<<<NB, 256, 0, stream>>>(base, parts, cursor, N, E);

    // node GEMM with fused score columns
    k0_wa<<<1, 256, 0, stream>>>(W, a, wa);
    k0_swz<<<(8 * 4 * LCOLS * 8) / 256, 256, 0, stream>>>(W, wa, wb);
    const int ngroups = (N + 15) / 16;
    k1_mfma<<<1024, 256, 0, stream>>>(x, wb, hb, s_src, s_dst, N, ngroups);

    // chunked scatter, then fused gather + normalize
    k_scatter8<<<2048, 256, 0, stream>>>(ei, cursor, csr, E, chunk_n);
    k2_gather<<<(N + 15) / 16, 256, 0, stream>>>(csr, base, hb, s_src, s_dst, out, N);
}

// Round 8
// 209.718 us; speedup vs baseline: 1.3527x; 1.1566x over previous
//
#include <hip/hip_runtime.h>
#include <hip/hip_bf16.h>
#include <math.h>

#define IN_DIM 256
#define OUT_DIM 64
#define NEG_SLOPE 0.2f
#define LCOLS 80        // 64 h-cols + 16-col score tile (col64=Wa_s, col65=Wa_d)
#define NBMAX 392       // max dst-buckets (256 nodes each) for N <= 100352
#define ECAP  6656      // per-bucket slot capacity (multiple of 16)
#define SENT  0xFFFFFFFFu

typedef __attribute__((ext_vector_type(8))) short bf16x8;
typedef __attribute__((ext_vector_type(4))) float f32x4;

static __device__ __forceinline__ ushort f2bf(float f) {
    union { __hip_bfloat16 b; ushort u; } cv;
    cv.b = __float2bfloat16(f);
    return cv.u;
}
static __device__ __forceinline__ float bf2f(ushort u) {
    union { ushort u2[2]; float f; } cv;
    cv.u2[0] = 0; cv.u2[1] = u;
    return cv.f;
}

// ---------------------------------------------------------------------------
// k0_wa: Wa_s[k] = W[k,:]·a[:64], Wa_d[k] = W[k,:]·a[64:]. One block.
// ---------------------------------------------------------------------------
__global__ __launch_bounds__(256) void k0_wa(
        const float* __restrict__ W, const float* __restrict__ a,
        float* __restrict__ wa)
{
    const int k = threadIdx.x;
    const float* wr = W + (size_t)k * OUT_DIM;
    float ss = 0.f, sd = 0.f;
    #pragma unroll
    for (int j = 0; j < OUT_DIM; ++j) {
        const float w = wr[j];
        ss = fmaf(w, a[j], ss);
        sd = fmaf(w, a[OUT_DIM + j], sd);
    }
    wa[k] = ss;
    wa[IN_DIM + k] = sd;
}

// ---------------------------------------------------------------------------
// k0_swz: pre-swizzled bf16 B-tile (8t x 4khi x 80col x 8j); cols 64/65 = Wa.
// ---------------------------------------------------------------------------
__global__ __launch_bounds__(256) void k0_swz(
        const float* __restrict__ W, const float* __restrict__ wa,
        ushort* __restrict__ wb)
{
    const int idx = blockIdx.x * 256 + threadIdx.x;
    const int j   = idx & 7;
    const int col = (idx >> 3) % LCOLS;
    const int tk  = (idx >> 3) / LCOLS;
    const int k   = (tk >> 2) * 32 + (tk & 3) * 8 + j;
    float v = 0.f;
    if (col < OUT_DIM)           v = W[(size_t)k * OUT_DIM + col];
    else if (col == OUT_DIM)     v = wa[k];
    else if (col == OUT_DIM + 1) v = wa[IN_DIM + k];
    wb[idx] = f2bf(v);
}

// ---------------------------------------------------------------------------
// K1: h = x @ W via bf16 MFMA 16x16x32, scores fused as B-cols 64/65.
// (unchanged from R7 — next round's target)
// ---------------------------------------------------------------------------
__global__ __launch_bounds__(256) void k1_mfma(
        const float* __restrict__ x, const ushort* __restrict__ wb,
        ushort* __restrict__ hb, float* __restrict__ s_src,
        float* __restrict__ s_dst, int N, int ngroups)
{
    __shared__ ushort w_lds[8 * 4 * LCOLS * 8];          // 40960 B

    const int tid = threadIdx.x;
    for (int i = tid; i < (8 * 4 * LCOLS * 8) / 8; i += 256)
        ((float4*)w_lds)[i] = ((const float4*)wb)[i];
    __syncthreads();

    const int lane = tid & 63;
    const int l15  = lane & 15;
    const int khi  = lane >> 4;

    const int gw = blockIdx.x * 4 + (tid >> 6);
    const int nw = gridDim.x * 4;

    float4 raw[16];
    int g = gw;
    if (g < ngroups) {
        const int node = min(g * 16 + l15, N - 1);
        const float* xp = x + (size_t)node * IN_DIM + khi * 8;
        #pragma unroll
        for (int t = 0; t < 8; ++t) {
            raw[2 * t]     = *(const float4*)(xp + t * 32);
            raw[2 * t + 1] = *(const float4*)(xp + t * 32 + 4);
        }
    }

    for (; g < ngroups; g += nw) {
        bf16x8 af[8];
        #pragma unroll
        for (int t = 0; t < 8; ++t) {
            union { bf16x8 v; ushort u[8]; } pk;
            pk.u[0] = f2bf(raw[2*t].x);   pk.u[1] = f2bf(raw[2*t].y);
            pk.u[2] = f2bf(raw[2*t].z);   pk.u[3] = f2bf(raw[2*t].w);
            pk.u[4] = f2bf(raw[2*t+1].x); pk.u[5] = f2bf(raw[2*t+1].y);
            pk.u[6] = f2bf(raw[2*t+1].z); pk.u[7] = f2bf(raw[2*t+1].w);
            af[t] = pk.v;
        }

        const int gn = g + nw;
        if (gn < ngroups) {
            const int node = min(gn * 16 + l15, N - 1);
            const float* xp = x + (size_t)node * IN_DIM + khi * 8;
            #pragma unroll
            for (int t = 0; t < 8; ++t) {
                raw[2 * t]     = *(const float4*)(xp + t * 32);
                raw[2 * t + 1] = *(const float4*)(xp + t * 32 + 4);
            }
        }

        f32x4 acc[5] = {{0,0,0,0},{0,0,0,0},{0,0,0,0},{0,0,0,0},{0,0,0,0}};
        #pragma unroll
        for (int t = 0; t < 8; ++t) {
            const bf16x8* wp = (const bf16x8*)w_lds + (t * 4 + khi) * LCOLS + l15;
            #pragma unroll
            for (int c = 0; c < 5; ++c)
                acc[c] = __builtin_amdgcn_mfma_f32_16x16x32_bf16(
                             af[t], wp[c * 16], acc[c], 0, 0, 0);
        }

        const int row0 = g * 16 + khi * 4;
        #pragma unroll
        for (int r = 0; r < 4; ++r) {
            const int nrow = row0 + r;
            if (nrow < N) {
                #pragma unroll
                for (int c = 0; c < 4; ++c)
                    hb[(size_t)nrow * OUT_DIM + c * 16 + l15] = f2bf(acc[c][r]);
                if (l15 == 0) s_src[nrow] = acc[4][r];
                if (l15 == 1) s_dst[nrow] = acc[4][r];
            }
        }
    }
}

// ---------------------------------------------------------------------------
// kA_bin: one pass over edges -> 391 fine buckets (256 dsts each).
// Per-block LDS ring rows (32 slots); flushes are EXACT 16-entry (64B),
// 64B-ALIGNED chunks (tails advance in multiples of 16) -> no partial-line
// HBM writes. Residuals padded with SENT sentinels.
// Entry = src (17b) | dst_local (8b) << 17.
// ---------------------------------------------------------------------------
__global__ __launch_bounds__(256) void kA_bin(
        const int* __restrict__ ei, int* __restrict__ gtail,
        unsigned int* __restrict__ ebuf, int E, int nbuck)
{
    __shared__ unsigned int lbuf[NBMAX][32];   // 50176 B
    __shared__ int lcnt[NBMAX];
    __shared__ int lfl[NBMAX];

    const int tid = threadIdx.x;
    for (int r = tid; r < nbuck; r += 256) { lcnt[r] = 0; lfl[r] = 0; }
    __syncthreads();

    const int e0 = (int)(((long long)blockIdx.x * E) / gridDim.x);
    const int e1 = (int)(((long long)(blockIdx.x + 1) * E) / gridDim.x);

    for (int b = e0; b < e1; b += 256) {
        const int i = b + tid;
        if (i < e1) {
            const unsigned int src = (unsigned int)ei[i];
            const int dst = ei[E + i];
            const int c = dst >> 8;
            const int pos = atomicAdd(&lcnt[c], 1);
            lbuf[c][pos & 31] = src | ((unsigned int)(dst & 255) << 17);
        }
        __syncthreads();
        for (int r = tid; r < nbuck; r += 256) {
            int cnt = lcnt[r];
            int fl  = lfl[r];
            while (cnt - fl >= 16) {
                const int gb = atomicAdd(&gtail[r], 16);
                if (gb + 16 <= ECAP) {
                    uint4* dp = (uint4*)(ebuf + (size_t)r * ECAP + gb);
                    const uint4* sp = (const uint4*)&lbuf[r][fl & 31];
                    dp[0] = sp[0]; dp[1] = sp[1]; dp[2] = sp[2]; dp[3] = sp[3];
                }
                fl += 16;
            }
            lfl[r] = fl;
        }
        __syncthreads();
    }

    // drain (<=15 entries per row remain; one padded chunk each)
    for (int r = tid; r < nbuck; r += 256) {
        const int cnt = lcnt[r];
        const int fl  = lfl[r];
        if (cnt > fl) {
            const int gb = atomicAdd(&gtail[r], 16);
            if (gb + 16 <= ECAP) {
                unsigned int tmp[16];
                #pragma unroll
                for (int k = 0; k < 16; ++k)
                    tmp[k] = (fl + k < cnt) ? lbuf[r][(fl + k) & 31] : SENT;
                uint4* dp = (uint4*)(ebuf + (size_t)r * ECAP + gb);
                #pragma unroll
                for (int k = 0; k < 4; ++k)
                    dp[k] = make_uint4(tmp[4*k], tmp[4*k+1], tmp[4*k+2], tmp[4*k+3]);
            }
        }
    }
}

// ---------------------------------------------------------------------------
// k2_bucket: 2 blocks per bucket (dst halves of 128). Re-stream the ~26KB
// bucket region (L2-resident) twice: LDS hist -> scan -> LDS counting-sort;
// then quarter-wave-per-dst gather/softmax (R7-proven core) reading edge
// lists from LDS. out rows written contiguously. No global scatter anywhere.
// ---------------------------------------------------------------------------
__global__ __launch_bounds__(256) void k2_bucket(
        const unsigned int* __restrict__ ebuf, const int* __restrict__ gtail,
        const ushort* __restrict__ hb, const float* __restrict__ s_src,
        const float* __restrict__ s_dst, float* __restrict__ out, int N)
{
    __shared__ int hist[128], base[128], cur[128];
    __shared__ int sorted[3072];

    const int B   = blockIdx.x >> 1;
    const int H   = blockIdx.x & 1;
    const int tid = threadIdx.x;
    const int slots = min(gtail[B], ECAP);
    const unsigned int* eb = ebuf + (size_t)B * ECAP;

    if (tid < 128) hist[tid] = 0;
    __syncthreads();

    for (int i = tid; i < slots; i += 256) {
        const unsigned int e = eb[i];
        if (e != SENT) {
            const int dl = (int)((e >> 17) & 255);
            if ((dl >> 7) == H) atomicAdd(&hist[dl & 127], 1);
        }
    }
    __syncthreads();
    if (tid == 0) {
        int acc = 0;
        for (int d = 0; d < 128; ++d) { base[d] = acc; acc += hist[d]; }
    }
    __syncthreads();
    if (tid < 128) cur[tid] = base[tid];
    __syncthreads();
    for (int i = tid; i < slots; i += 256) {
        const unsigned int e = eb[i];
        if (e != SENT) {
            const int dl = (int)((e >> 17) & 255);
            if ((dl >> 7) == H) {
                const int pos = atomicAdd(&cur[dl & 127], 1);
                if (pos < 3072) sorted[pos] = (int)(e & 0x1FFFF);
            }
        }
    }
    __syncthreads();

    const int l15   = tid & 15;
    const int qw    = tid >> 4;          // 0..15 (block-level quarter index)
    const int qbase = tid & 48;          // quarter base lane within wave
    const int dgb   = B * 256 + H * 128;

    for (int k = 0; k < 8; ++k) {
        const int d  = qw + 16 * k;
        const int dg = dgb + d;
        if (dg >= N) continue;
        const int beg = base[d];
        const int cnt = hist[d];
        const float sd = s_dst[dg];

        float a0 = 0.f, a1 = 0.f, a2 = 0.f, a3 = 0.f, den = 0.f;
        for (int b = 0; b < cnt; b += 16) {
            const int m = min(16, cnt - b);
            int srcj = 0; float exj = 0.f;
            if (l15 < m) {
                srcj = sorted[beg + b + l15];
                float sc = s_src[srcj] + sd;
                sc = (sc > 0.f) ? sc : NEG_SLOPE * sc;
                exj = __expf(sc);
            }
            float t = exj;
            t += __shfl_xor(t, 1, 64);
            t += __shfl_xor(t, 2, 64);
            t += __shfl_xor(t, 4, 64);
            t += __shfl_xor(t, 8, 64);
            den += t;

            #pragma unroll 4
            for (int j = 0; j < m; ++j) {
                const int   s  = __shfl(srcj, qbase + j, 64);
                const float ex = __shfl(exj,  qbase + j, 64);
                const ushort4 hv = *(const ushort4*)(hb + ((size_t)s << 6) + (l15 << 2));
                a0 = fmaf(ex, bf2f(hv.x), a0);
                a1 = fmaf(ex, bf2f(hv.y), a1);
                a2 = fmaf(ex, bf2f(hv.z), a2);
                a3 = fmaf(ex, bf2f(hv.w), a3);
            }
        }
        const float r = (cnt > 0) ? 1.f / den : 0.f;
        float4 v;
        v.x = a0 * r; v.y = a1 * r; v.z = a2 * r; v.w = a3 * r;
        *(float4*)(out + ((size_t)dg << 6) + (l15 << 2)) = v;
    }
}

extern "C" void kernel_launch(void* const* d_in, const int* in_sizes, int n_in,
                              void* d_out, int out_size, void* d_ws, size_t ws_size,
                              hipStream_t stream)
{
    const float* x  = (const float*)d_in[0];
    const float* W  = (const float*)d_in[1];
    const float* a  = (const float*)d_in[2];
    const int*   ei = (const int*)d_in[3];

    const int N = in_sizes[0] / IN_DIM;     // 100000
    const int E = in_sizes[3] / 2;          // 1600000

    float* out = (float*)d_out;

    char* ws = (char*)d_ws;
    ushort* hb     = (ushort*)ws;                  ws += (size_t)N * OUT_DIM * 2; // 12.8 MB
    float*  s_src  = (float*)ws;                   ws += (size_t)N * 4;
    float*  s_dst  = (float*)ws;                   ws += (size_t)N * 4;
    float*  wa     = (float*)ws;                   ws += 2 * IN_DIM * 4;
    ushort* wb     = (ushort*)ws;                  ws += 8 * 4 * LCOLS * 8 * 2;   // 40 KB
    int*    gtail  = (int*)ws;                     ws += 512 * 4;                 // 64B-aligned pad
    unsigned int* ebuf = (unsigned int*)ws;        ws += (size_t)NBMAX * ECAP * 4; // ~10.4 MB

    const int nbuck = (N + 255) >> 8;              // 391

    hipMemsetAsync(gtail, 0, 512 * 4, stream);

    // single-pass binning (no hist/scan/scatter kernels anymore)
    kA_bin<<<128, 256, 0, stream>>>(ei, gtail, ebuf, E, nbuck);

    // node GEMM with fused score columns
    k0_wa<<<1, 256, 0, stream>>>(W, a, wa);
    k0_swz<<<(8 * 4 * LCOLS * 8) / 256, 256, 0, stream>>>(W, wa, wb);
    const int ngroups = (N + 15) / 16;
    k1_mfma<<<1024, 256, 0, stream>>>(x, wb, hb, s_src, s_dst, N, ngroups);

    // bucket-local sort + fused gather/softmax/normalize
    k2_bucket<<<nbuck * 2, 256, 0, stream>>>(ebuf, gtail, hb, s_src, s_dst, out, N);
}

// Round 9
// 142.246 us; speedup vs baseline: 1.9943x; 1.4743x over previous
//
#include <hip/hip_runtime.h>
#include <hip/hip_bf16.h>
#include <math.h>

#define IN_DIM 256
#define OUT_DIM 64
#define NEG_SLOPE 0.2f
#define LCOLS 80        // 64 h-cols + 16-col score tile (col64=Wa_s, col65=Wa_d)
#define NBMAX 392       // max dst-buckets (256 nodes each) for N <= 100352
#define ECAP  10240     // per-bucket slot capacity (multiple of 16)
#define SENT  0xFFFFFFFFu
#define SCAP  2560      // per-block sorted-pair capacity (64 dsts, mean 1024)

typedef __attribute__((ext_vector_type(8))) short bf16x8;
typedef __attribute__((ext_vector_type(4))) float f32x4;

static __device__ __forceinline__ ushort f2bf(float f) {
    union { __hip_bfloat16 b; ushort u; } cv;
    cv.b = __float2bfloat16(f);
    return cv.u;
}
static __device__ __forceinline__ float bf2f(ushort u) {
    union { ushort u2[2]; float f; } cv;
    cv.u2[0] = 0; cv.u2[1] = u;
    return cv.f;
}

// ---------------------------------------------------------------------------
// k0_wa: Wa_s[k] = W[k,:]·a[:64], Wa_d[k] = W[k,:]·a[64:]. One block.
// ---------------------------------------------------------------------------
__global__ __launch_bounds__(256) void k0_wa(
        const float* __restrict__ W, const float* __restrict__ a,
        float* __restrict__ wa)
{
    const int k = threadIdx.x;
    const float* wr = W + (size_t)k * OUT_DIM;
    float ss = 0.f, sd = 0.f;
    #pragma unroll
    for (int j = 0; j < OUT_DIM; ++j) {
        const float w = wr[j];
        ss = fmaf(w, a[j], ss);
        sd = fmaf(w, a[OUT_DIM + j], sd);
    }
    wa[k] = ss;
    wa[IN_DIM + k] = sd;
}

// ---------------------------------------------------------------------------
// k0_swz: pre-swizzled bf16 B-tile (8t x 4khi x 80col x 8j); cols 64/65 = Wa.
// ---------------------------------------------------------------------------
__global__ __launch_bounds__(256) void k0_swz(
        const float* __restrict__ W, const float* __restrict__ wa,
        ushort* __restrict__ wb)
{
    const int idx = blockIdx.x * 256 + threadIdx.x;
    const int j   = idx & 7;
    const int col = (idx >> 3) % LCOLS;
    const int tk  = (idx >> 3) / LCOLS;
    const int k   = (tk >> 2) * 32 + (tk & 3) * 8 + j;
    float v = 0.f;
    if (col < OUT_DIM)           v = W[(size_t)k * OUT_DIM + col];
    else if (col == OUT_DIM)     v = wa[k];
    else if (col == OUT_DIM + 1) v = wa[IN_DIM + k];
    wb[idx] = f2bf(v);
}

// ---------------------------------------------------------------------------
// K1: h = x @ W via bf16 MFMA 16x16x32, scores fused as B-cols 64/65.
// (unchanged — isolation; target for a later round)
// ---------------------------------------------------------------------------
__global__ __launch_bounds__(256) void k1_mfma(
        const float* __restrict__ x, const ushort* __restrict__ wb,
        ushort* __restrict__ hb, float* __restrict__ s_src,
        float* __restrict__ s_dst, int N, int ngroups)
{
    __shared__ ushort w_lds[8 * 4 * LCOLS * 8];          // 40960 B

    const int tid = threadIdx.x;
    for (int i = tid; i < (8 * 4 * LCOLS * 8) / 8; i += 256)
        ((float4*)w_lds)[i] = ((const float4*)wb)[i];
    __syncthreads();

    const int lane = tid & 63;
    const int l15  = lane & 15;
    const int khi  = lane >> 4;

    const int gw = blockIdx.x * 4 + (tid >> 6);
    const int nw = gridDim.x * 4;

    float4 raw[16];
    int g = gw;
    if (g < ngroups) {
        const int node = min(g * 16 + l15, N - 1);
        const float* xp = x + (size_t)node * IN_DIM + khi * 8;
        #pragma unroll
        for (int t = 0; t < 8; ++t) {
            raw[2 * t]     = *(const float4*)(xp + t * 32);
            raw[2 * t + 1] = *(const float4*)(xp + t * 32 + 4);
        }
    }

    for (; g < ngroups; g += nw) {
        bf16x8 af[8];
        #pragma unroll
        for (int t = 0; t < 8; ++t) {
            union { bf16x8 v; ushort u[8]; } pk;
            pk.u[0] = f2bf(raw[2*t].x);   pk.u[1] = f2bf(raw[2*t].y);
            pk.u[2] = f2bf(raw[2*t].z);   pk.u[3] = f2bf(raw[2*t].w);
            pk.u[4] = f2bf(raw[2*t+1].x); pk.u[5] = f2bf(raw[2*t+1].y);
            pk.u[6] = f2bf(raw[2*t+1].z); pk.u[7] = f2bf(raw[2*t+1].w);
            af[t] = pk.v;
        }

        const int gn = g + nw;
        if (gn < ngroups) {
            const int node = min(gn * 16 + l15, N - 1);
            const float* xp = x + (size_t)node * IN_DIM + khi * 8;
            #pragma unroll
            for (int t = 0; t < 8; ++t) {
                raw[2 * t]     = *(const float4*)(xp + t * 32);
                raw[2 * t + 1] = *(const float4*)(xp + t * 32 + 4);
            }
        }

        f32x4 acc[5] = {{0,0,0,0},{0,0,0,0},{0,0,0,0},{0,0,0,0},{0,0,0,0}};
        #pragma unroll
        for (int t = 0; t < 8; ++t) {
            const bf16x8* wp = (const bf16x8*)w_lds + (t * 4 + khi) * LCOLS + l15;
            #pragma unroll
            for (int c = 0; c < 5; ++c)
                acc[c] = __builtin_amdgcn_mfma_f32_16x16x32_bf16(
                             af[t], wp[c * 16], acc[c], 0, 0, 0);
        }

        const int row0 = g * 16 + khi * 4;
        #pragma unroll
        for (int r = 0; r < 4; ++r) {
            const int nrow = row0 + r;
            if (nrow < N) {
                #pragma unroll
                for (int c = 0; c < 4; ++c)
                    hb[(size_t)nrow * OUT_DIM + c * 16 + l15] = f2bf(acc[c][r]);
                if (l15 == 0) s_src[nrow] = acc[4][r];
                if (l15 == 1) s_dst[nrow] = acc[4][r];
            }
        }
    }
}

// ---------------------------------------------------------------------------
// kA_bin: one pass over edges -> 391 fine buckets (256 dsts each).
// 512 blocks (2/CU). LDS ring rows (32 slots); flushes are exact 16-entry,
// 64B-aligned chunks; residuals padded with SENT. Entry = src|dl<<17.
// ---------------------------------------------------------------------------
__global__ __launch_bounds__(256) void kA_bin(
        const int* __restrict__ ei, int* __restrict__ gtail,
        unsigned int* __restrict__ ebuf, int E, int nbuck)
{
    __shared__ unsigned int lbuf[NBMAX][32];   // 50176 B
    __shared__ int lcnt[NBMAX];
    __shared__ int lfl[NBMAX];

    const int tid = threadIdx.x;
    for (int r = tid; r < nbuck; r += 256) { lcnt[r] = 0; lfl[r] = 0; }
    __syncthreads();

    const int e0 = (int)(((long long)blockIdx.x * E) / gridDim.x);
    const int e1 = (int)(((long long)(blockIdx.x + 1) * E) / gridDim.x);

    for (int b = e0; b < e1; b += 256) {
        const int i = b + tid;
        if (i < e1) {
            const unsigned int src = (unsigned int)ei[i];
            const int dst = ei[E + i];
            const int c = dst >> 8;
            const int pos = atomicAdd(&lcnt[c], 1);
            lbuf[c][pos & 31] = src | ((unsigned int)(dst & 255) << 17);
        }
        __syncthreads();
        for (int r = tid; r < nbuck; r += 256) {
            int cnt = lcnt[r];
            int fl  = lfl[r];
            while (cnt - fl >= 16) {
                const int gb = atomicAdd(&gtail[r], 16);
                if (gb + 16 <= ECAP) {
                    uint4* dp = (uint4*)(ebuf + (size_t)r * ECAP + gb);
                    const uint4* sp = (const uint4*)&lbuf[r][fl & 31];
                    dp[0] = sp[0]; dp[1] = sp[1]; dp[2] = sp[2]; dp[3] = sp[3];
                }
                fl += 16;
            }
            lfl[r] = fl;
        }
        __syncthreads();
    }

    for (int r = tid; r < nbuck; r += 256) {
        const int cnt = lcnt[r];
        const int fl  = lfl[r];
        if (cnt > fl) {
            const int gb = atomicAdd(&gtail[r], 16);
            if (gb + 16 <= ECAP) {
                unsigned int tmp[16];
                #pragma unroll
                for (int k = 0; k < 16; ++k)
                    tmp[k] = (fl + k < cnt) ? lbuf[r][(fl + k) & 31] : SENT;
                uint4* dp = (uint4*)(ebuf + (size_t)r * ECAP + gb);
                #pragma unroll
                for (int k = 0; k < 4; ++k)
                    dp[k] = make_uint4(tmp[4*k], tmp[4*k+1], tmp[4*k+2], tmp[4*k+3]);
            }
        }
    }
}

// ---------------------------------------------------------------------------
// k2_bucket v3: 4 blocks per bucket (64 dsts each; grid 1564, ~21KB LDS ->
// all blocks resident). Pass 1: hist. One-wave shfl scan. Pass 2: counting-
// sort placement FUSED with scoring -> spair[pos] = {src, ex}. Gather:
// quarter-wave per dst, uniform ds_read_b64 of (src,ex) (zero bpermutes),
// den accumulated redundantly per lane, unroll-4 8B hb gathers, per-lane
// 4-col accumulators -> direct float4 store.
// ---------------------------------------------------------------------------
__global__ __launch_bounds__(256) void k2_bucket(
        const unsigned int* __restrict__ ebuf, const int* __restrict__ gtail,
        const ushort* __restrict__ hb, const float* __restrict__ s_src,
        const float* __restrict__ s_dst, float* __restrict__ out, int N)
{
    __shared__ int hist[64], bse[64], cur[64];
    __shared__ float sdl[64];
    __shared__ int2 spair[SCAP];

    const int B   = blockIdx.x >> 2;
    const int H   = blockIdx.x & 3;
    const int tid = threadIdx.x;
    const int slots = min(gtail[B], ECAP);
    const unsigned int* eb = ebuf + (size_t)B * ECAP;
    const int dgb = B * 256 + H * 64;

    if (tid < 64) {
        hist[tid] = 0;
        const int dg = dgb + tid;
        sdl[tid] = (dg < N) ? s_dst[dg] : 0.f;
    }
    __syncthreads();

    // pass 1: histogram of this block's 64 dsts
    for (int i = tid; i < slots; i += 256) {
        const unsigned int e = eb[i];
        if (e != SENT) {
            const int dl = (int)((e >> 17) & 255);
            if ((dl >> 6) == H) atomicAdd(&hist[dl & 63], 1);
        }
    }
    __syncthreads();

    // one-wave exclusive scan of 64 counts
    if (tid < 64) {
        const int v = hist[tid];
        int s = v;
        #pragma unroll
        for (int off = 1; off < 64; off <<= 1) {
            const int u = __shfl_up(s, off, 64);
            if (tid >= off) s += u;
        }
        bse[tid] = s - v;
        cur[tid] = s - v;
    }
    __syncthreads();

    // pass 2: placement fused with scoring
    for (int i = tid; i < slots; i += 256) {
        const unsigned int e = eb[i];
        if (e != SENT) {
            const int dl = (int)((e >> 17) & 255);
            if ((dl >> 6) == H) {
                const int src = (int)(e & 0x1FFFF);
                const int d   = dl & 63;
                float sc = s_src[src] + sdl[d];
                sc = (sc > 0.f) ? sc : NEG_SLOPE * sc;
                const int pos = atomicAdd(&cur[d], 1);
                if (pos < SCAP)
                    spair[pos] = make_int2(src, __float_as_int(__expf(sc)));
            }
        }
    }
    __syncthreads();

    // gather: quarter-wave per dst, 4 dsts per quarter
    const int l15 = tid & 15;
    const int qw  = tid >> 4;
    #pragma unroll
    for (int k = 0; k < 4; ++k) {
        const int d  = qw + 16 * k;
        const int dg = dgb + d;
        if (dg >= N) continue;
        const int beg = bse[d];
        const int cnt = hist[d];
        const int je0 = min(beg, SCAP);
        const int je1 = min(beg + cnt, SCAP);
        const int m   = je1 - je0;

        float a0 = 0.f, a1 = 0.f, a2 = 0.f, a3 = 0.f, den = 0.f;
        #pragma unroll 4
        for (int j = 0; j < m; ++j) {
            const int2 p = spair[je0 + j];           // uniform in quarter
            const float ex = __int_as_float(p.y);
            den += ex;
            const ushort4 hv = *(const ushort4*)(hb + ((size_t)p.x << 6) + (l15 << 2));
            a0 = fmaf(ex, bf2f(hv.x), a0);
            a1 = fmaf(ex, bf2f(hv.y), a1);
            a2 = fmaf(ex, bf2f(hv.z), a2);
            a3 = fmaf(ex, bf2f(hv.w), a3);
        }
        const float r = (m > 0) ? 1.f / den : 0.f;
        float4 v;
        v.x = a0 * r; v.y = a1 * r; v.z = a2 * r; v.w = a3 * r;
        *(float4*)(out + ((size_t)dg << 6) + (l15 << 2)) = v;
    }
}

extern "C" void kernel_launch(void* const* d_in, const int* in_sizes, int n_in,
                              void* d_out, int out_size, void* d_ws, size_t ws_size,
                              hipStream_t stream)
{
    const float* x  = (const float*)d_in[0];
    const float* W  = (const float*)d_in[1];
    const float* a  = (const float*)d_in[2];
    const int*   ei = (const int*)d_in[3];

    const int N = in_sizes[0] / IN_DIM;     // 100000
    const int E = in_sizes[3] / 2;          // 1600000

    float* out = (float*)d_out;

    char* ws = (char*)d_ws;
    ushort* hb     = (ushort*)ws;                  ws += (size_t)N * OUT_DIM * 2; // 12.8 MB
    float*  s_src  = (float*)ws;                   ws += (size_t)N * 4;
    float*  s_dst  = (float*)ws;                   ws += (size_t)N * 4;
    float*  wa     = (float*)ws;                   ws += 2 * IN_DIM * 4;
    ushort* wb     = (ushort*)ws;                  ws += 8 * 4 * LCOLS * 8 * 2;   // 40 KB
    int*    gtail  = (int*)ws;                     ws += 512 * 4;
    unsigned int* ebuf = (unsigned int*)ws;        ws += (size_t)NBMAX * ECAP * 4; // ~16 MB

    const int nbuck = (N + 255) >> 8;              // 391

    hipMemsetAsync(gtail, 0, 512 * 4, stream);

    // single-pass binning
    kA_bin<<<512, 256, 0, stream>>>(ei, gtail, ebuf, E, nbuck);

    // node GEMM with fused score columns
    k0_wa<<<1, 256, 0, stream>>>(W, a, wa);
    k0_swz<<<(8 * 4 * LCOLS * 8) / 256, 256, 0, stream>>>(W, wa, wb);
    const int ngroups = (N + 15) / 16;
    k1_mfma<<<1024, 256, 0, stream>>>(x, wb, hb, s_src, s_dst, N, ngroups);

    // bucket-local sort+score, fused gather/softmax/normalize
    k2_bucket<<<nbuck * 4, 256, 0, stream>>>(ebuf, gtail, hb, s_src, s_dst, out, N);
}